// Round 5
// baseline (665.538 us; speedup 1.0000x reference)
//
#include <hip/hip_runtime.h>
#include <math.h>

#define BB 256
#define SS 257
#define CVD 1024
#define CTD 768
#define NTOK 256          // S-1
#define MROWS 1024        // B*4
#define EPS_LN 1e-5f
#define NEG_SLOPE 0.01f
#define LDKP 72           // LDS k-stride (64 + 8 pad) in bf16 elems -> 144B rows, 2-way banks (free)

typedef __bf16 bf16x8 __attribute__((ext_vector_type(8)));
typedef float f32x4 __attribute__((ext_vector_type(4)));
typedef unsigned short usx8 __attribute__((ext_vector_type(8)));
typedef unsigned short usx4 __attribute__((ext_vector_type(4)));

__device__ __forceinline__ unsigned short f2bf(float x) {
    unsigned u = __float_as_uint(x);
    unsigned r = u + 0x7FFFu + ((u >> 16) & 1u);   // round-to-nearest-even
    return (unsigned short)(r >> 16);
}
__device__ __forceinline__ float bf2f(unsigned short h) {
    return __uint_as_float(((unsigned)h) << 16);
}
__device__ __forceinline__ void cvt4(float a, float b, float c, float d, usx4& h, usx4& l) {
    h[0] = f2bf(a); l[0] = f2bf(a - bf2f(h[0]));
    h[1] = f2bf(b); l[1] = f2bf(b - bf2f(h[1]));
    h[2] = f2bf(c); l[2] = f2bf(c - bf2f(h[2]));
    h[3] = f2bf(d); l[3] = f2bf(d - bf2f(h[3]));
}

// ============ fused front-end: cos_sim + top-3 + gather + fp32->bf16(hi,lo) ===
// one block per batch; 8 waves; cos values stay in LDS; gathered rows L2-hot.
__global__ __launch_bounds__(512) void front_kernel(const float* __restrict__ vis,
                                                    const float* __restrict__ inf,
                                                    unsigned short* __restrict__ x0h,
                                                    unsigned short* __restrict__ x0l) {
    __shared__ float cosv[NTOK];
    __shared__ int sidx[3];
    int b = blockIdx.x;
    int t = threadIdx.x;
    int wave = t >> 6, lane = t & 63;
    const float* vbase = vis + (size_t)b * SS * CVD;
    const float* ibase = inf + (size_t)b * SS * CVD;

    // ---- cos phase: each wave does 32 token rows, 2-row unrolled for MLP ----
    for (int u = 0; u < 16; ++u) {
        int r0 = wave * 32 + u * 2;
        const float4* v0 = (const float4*)(vbase + (size_t)(r0 + 1) * CVD);
        const float4* i0 = (const float4*)(ibase + (size_t)(r0 + 1) * CVD);
        const float4* v1 = (const float4*)(vbase + (size_t)(r0 + 2) * CVD);
        const float4* i1 = (const float4*)(ibase + (size_t)(r0 + 2) * CVD);
        float vv0 = 0.f, ii0 = 0.f, vi0 = 0.f;
        float vv1 = 0.f, ii1 = 0.f, vi1 = 0.f;
#pragma unroll
        for (int j = 0; j < 4; ++j) {
            float4 a = v0[j * 64 + lane];
            float4 c = i0[j * 64 + lane];
            float4 d = v1[j * 64 + lane];
            float4 e = i1[j * 64 + lane];
            vv0 += a.x * a.x + a.y * a.y + a.z * a.z + a.w * a.w;
            ii0 += c.x * c.x + c.y * c.y + c.z * c.z + c.w * c.w;
            vi0 += a.x * c.x + a.y * c.y + a.z * c.z + a.w * c.w;
            vv1 += d.x * d.x + d.y * d.y + d.z * d.z + d.w * d.w;
            ii1 += e.x * e.x + e.y * e.y + e.z * e.z + e.w * e.w;
            vi1 += d.x * e.x + d.y * e.y + d.z * e.z + d.w * e.w;
        }
#pragma unroll
        for (int off = 32; off; off >>= 1) {
            vv0 += __shfl_xor(vv0, off);
            ii0 += __shfl_xor(ii0, off);
            vi0 += __shfl_xor(vi0, off);
            vv1 += __shfl_xor(vv1, off);
            ii1 += __shfl_xor(ii1, off);
            vi1 += __shfl_xor(vi1, off);
        }
        if (lane == 0) {
            cosv[r0] = vi0 / sqrtf(vv0 * ii0);
            cosv[r0 + 1] = vi1 / sqrtf(vv1 * ii1);
        }
    }
    __syncthreads();

    // ---- top-3 (wave 0 only; ties -> lower index, matching lax.top_k) -------
    if (wave == 0) {
        float v[4];
        int id[4];
#pragma unroll
        for (int j = 0; j < 4; ++j) {
            id[j] = lane + j * 64;
            v[j] = cosv[id[j]];
        }
        for (int round = 0; round < 3; ++round) {
            float bv = v[0];
            int bi = id[0];
#pragma unroll
            for (int j = 1; j < 4; ++j)
                if (v[j] > bv) { bv = v[j]; bi = id[j]; }
#pragma unroll
            for (int off = 32; off; off >>= 1) {
                float ov = __shfl_xor(bv, off);
                int oi = __shfl_xor(bi, off);
                if (ov > bv || (ov == bv && oi < bi)) { bv = ov; bi = oi; }
            }
            if (lane == 0) sidx[round] = bi;
#pragma unroll
            for (int j = 0; j < 4; ++j)
                if (id[j] == bi) v[j] = -3.402823466e38f;
        }
    }
    __syncthreads();

    // ---- gather + concat + hi/lo bf16 conversion (rows are L2-hot) ----------
    int c = t & 255;
    int half = (t >> 8);               // 0: vis half, 1: inf half (wave-uniform)
    const float* src_base = half ? ibase : vbase;
#pragma unroll
    for (int rr = 0; rr < 4; ++rr) {
        int tok = (rr < 3) ? (sidx[rr] + 1) : 0;
        float4 a = ((const float4*)(src_base + (size_t)tok * CVD))[c];
        usx4 h, l;
        cvt4(a.x, a.y, a.z, a.w, h, l);
        size_t off = (size_t)(b * 4 + rr) * 2048 + half * 1024 + c * 4;
        *(usx4*)(x0h + off) = h;
        *(usx4*)(x0l + off) = l;
    }
}

// ============ fused weight prep: all 4 W -> bf16 hi/lo W^T ====================
__global__ __launch_bounds__(256) void wprep_all_kernel(
        const float* __restrict__ W0, unsigned short* __restrict__ W0h, unsigned short* __restrict__ W0l,
        const float* __restrict__ W1, unsigned short* __restrict__ W1h, unsigned short* __restrict__ W1l,
        const float* __restrict__ W2, unsigned short* __restrict__ W2h, unsigned short* __restrict__ W2l,
        const float* __restrict__ W3, unsigned short* __restrict__ W3h, unsigned short* __restrict__ W3l) {
    __shared__ float tile[64][69];
    int bid = blockIdx.x;
    const float* W;
    unsigned short *Th, *Tl;
    int K, N, k0, n0;
    if (bid < 512) {          // W0: 2048x1024, 32x16 tiles
        int q = bid;       W = W0; Th = W0h; Tl = W0l; K = 2048; N = 1024;
        k0 = (q & 31) * 64; n0 = (q >> 5) * 64;
    } else if (bid < 768) {   // W1: 1024x1024
        int q = bid - 512; W = W1; Th = W1h; Tl = W1l; K = 1024; N = 1024;
        k0 = (q & 15) * 64; n0 = (q >> 4) * 64;
    } else if (bid < 1024) {  // W2: 1024x1024
        int q = bid - 768; W = W2; Th = W2h; Tl = W2l; K = 1024; N = 1024;
        k0 = (q & 15) * 64; n0 = (q >> 4) * 64;
    } else {                  // W3: 1024x768, 16x12 tiles
        int q = bid - 1024; W = W3; Th = W3h; Tl = W3l; K = 1024; N = 768;
        k0 = (q & 15) * 64; n0 = (q >> 4) * 64;
    }
    int t = threadIdx.x;
    int r = t >> 4, c4 = (t & 15) * 4;
#pragma unroll
    for (int p = 0; p < 4; ++p) {
        float4 v = *(const float4*)(W + (size_t)(k0 + r + p * 16) * N + n0 + c4);
        tile[r + p * 16][c4 + 0] = v.x;
        tile[r + p * 16][c4 + 1] = v.y;
        tile[r + p * 16][c4 + 2] = v.z;
        tile[r + p * 16][c4 + 3] = v.w;
    }
    __syncthreads();
    int nn0 = t >> 4, kk = (t & 15) * 4;
#pragma unroll
    for (int p = 0; p < 4; ++p) {
        int nn = nn0 + p * 16;
        float a = tile[kk + 0][nn], b = tile[kk + 1][nn];
        float c = tile[kk + 2][nn], d = tile[kk + 3][nn];
        usx4 h, l;
        cvt4(a, b, c, d, h, l);
        *(usx4*)(Th + (size_t)(n0 + nn) * K + k0 + kk) = h;
        *(usx4*)(Tl + (size_t)(n0 + nn) * K + k0 + kk) = l;
    }
}

// ---------------- split-bf16 MFMA GEMM (unchanged, known-good) ----------------
__global__ __launch_bounds__(256, 1) void gemm_split_kernel(
        const unsigned short* __restrict__ Ah, const unsigned short* __restrict__ Al,
        const unsigned short* __restrict__ Bh, const unsigned short* __restrict__ Bl,
        float* __restrict__ Cpart, int N, int K, int KCH) {
    __shared__ unsigned short sAh[128 * LDKP], sAl[128 * LDKP];
    __shared__ unsigned short sBh[128 * LDKP], sBl[128 * LDKP];
    int t = threadIdx.x;
    int lane = t & 63, wid = t >> 6;
    int wm = (wid >> 1) * 64, wn = (wid & 1) * 64;
    int fr = lane & 15, kg = lane >> 4;
    int m0 = blockIdx.y * 128, n0 = blockIdx.x * 128;
    int kstart = blockIdx.z * KCH;
    int sm = t >> 1, skq = (t & 1) * 32;
    const usx8* gAh = (const usx8*)(Ah + (size_t)(m0 + sm) * K + kstart + skq);
    const usx8* gAl = (const usx8*)(Al + (size_t)(m0 + sm) * K + kstart + skq);
    const usx8* gBh = (const usx8*)(Bh + (size_t)(n0 + sm) * K + kstart + skq);
    const usx8* gBl = (const usx8*)(Bl + (size_t)(n0 + sm) * K + kstart + skq);

    f32x4 acc[4][4] = {};
    usx8 rah[4], ral[4], rbh[4], rbl[4];
    int nsteps = KCH >> 6;

#pragma unroll
    for (int s = 0; s < 4; ++s) { rah[s] = gAh[s]; ral[s] = gAl[s]; rbh[s] = gBh[s]; rbl[s] = gBl[s]; }

    for (int step = 0; step < nsteps; ++step) {
        int base = sm * LDKP + skq;
#pragma unroll
        for (int s = 0; s < 4; ++s) {
            *(usx8*)&sAh[base + s * 8] = rah[s];
            *(usx8*)&sAl[base + s * 8] = ral[s];
            *(usx8*)&sBh[base + s * 8] = rbh[s];
            *(usx8*)&sBl[base + s * 8] = rbl[s];
        }
        __syncthreads();
        if (step + 1 < nsteps) {
            int adv = (step + 1) * 8;
#pragma unroll
            for (int s = 0; s < 4; ++s) {
                rah[s] = gAh[adv + s]; ral[s] = gAl[adv + s];
                rbh[s] = gBh[adv + s]; rbl[s] = gBl[adv + s];
            }
        }
#pragma unroll
        for (int kc = 0; kc < 2; ++kc) {
            int kb = kc * 32 + kg * 8;
            bf16x8 ah[4], al[4];
#pragma unroll
            for (int i = 0; i < 4; ++i) {
                int ro = (wm + i * 16 + fr) * LDKP + kb;
                ah[i] = *(const bf16x8*)&sAh[ro];
                al[i] = *(const bf16x8*)&sAl[ro];
            }
#pragma unroll
            for (int j = 0; j < 4; ++j) {
                int co = (wn + j * 16 + fr) * LDKP + kb;
                bf16x8 bh = *(const bf16x8*)&sBh[co];
                bf16x8 bl = *(const bf16x8*)&sBl[co];
#pragma unroll
                for (int i = 0; i < 4; ++i) {
                    acc[i][j] = __builtin_amdgcn_mfma_f32_16x16x32_bf16(ah[i], bh, acc[i][j], 0, 0, 0);
                    acc[i][j] = __builtin_amdgcn_mfma_f32_16x16x32_bf16(ah[i], bl, acc[i][j], 0, 0, 0);
                    acc[i][j] = __builtin_amdgcn_mfma_f32_16x16x32_bf16(al[i], bh, acc[i][j], 0, 0, 0);
                }
            }
        }
        __syncthreads();
    }
    float* Cp = Cpart + (size_t)blockIdx.z * MROWS * N;
#pragma unroll
    for (int i = 0; i < 4; ++i) {
#pragma unroll
        for (int j = 0; j < 4; ++j) {
            int row = m0 + wm + i * 16 + kg * 4;
            int col = n0 + wn + j * 16 + fr;
#pragma unroll
            for (int r = 0; r < 4; ++r)
                Cp[(size_t)(row + r) * N + col] = acc[i][j][r];
        }
    }
}

// ---------------- block reduce helper ----------------------------------------
__device__ __forceinline__ float block_sum(float x, float* red) {
#pragma unroll
    for (int off = 32; off; off >>= 1) x += __shfl_xor(x, off);
    int wave = threadIdx.x >> 6, lane = threadIdx.x & 63;
    if (lane == 0) red[wave] = x;
    __syncthreads();
    float r = red[0] + red[1] + red[2] + red[3];
    __syncthreads();
    return r;
}

// ---------------- split-K reduce + bias + LN + leaky + bf16(hi,lo) ------------
__global__ __launch_bounds__(256) void reduce_ln_kernel(const float* __restrict__ Cp,
                                                        const float* __restrict__ bias,
                                                        const float* __restrict__ g,
                                                        const float* __restrict__ be,
                                                        unsigned short* __restrict__ Xh,
                                                        unsigned short* __restrict__ Xl) {
    __shared__ float red[4];
    int row = blockIdx.x, t = threadIdx.x;
    float4 y0 = ((const float4*)(Cp + (size_t)row * CVD))[t];
    float4 y1 = ((const float4*)(Cp + 1048576 + (size_t)row * CVD))[t];
    float4 y2 = ((const float4*)(Cp + 2097152 + (size_t)row * CVD))[t];
    float4 y3 = ((const float4*)(Cp + 3145728 + (size_t)row * CVD))[t];
    float4 bv = ((const float4*)bias)[t];
    float vx = y0.x + y1.x + y2.x + y3.x + bv.x;
    float vy = y0.y + y1.y + y2.y + y3.y + bv.y;
    float vz = y0.z + y1.z + y2.z + y3.z + bv.z;
    float vw = y0.w + y1.w + y2.w + y3.w + bv.w;
    float tot = block_sum(vx + vy + vz + vw, red);
    float mu = tot * (1.0f / CVD);
    float dx = vx - mu, dy = vy - mu, dz = vz - mu, dw = vw - mu;
    float tot2 = block_sum(dx * dx + dy * dy + dz * dz + dw * dw, red);
    float rstd = rsqrtf(tot2 * (1.0f / CVD) + EPS_LN);
    float4 gg = ((const float4*)g)[t];
    float4 bb = ((const float4*)be)[t];
    float ox = dx * rstd * gg.x + bb.x;
    float oy = dy * rstd * gg.y + bb.y;
    float oz = dz * rstd * gg.z + bb.z;
    float ow = dw * rstd * gg.w + bb.w;
    ox = ox >= 0.f ? ox : NEG_SLOPE * ox;
    oy = oy >= 0.f ? oy : NEG_SLOPE * oy;
    oz = oz >= 0.f ? oz : NEG_SLOPE * oz;
    ow = ow >= 0.f ? ow : NEG_SLOPE * ow;
    usx4 h, l;
    cvt4(ox, oy, oz, ow, h, l);
    *(usx4*)(Xh + (size_t)row * CVD + t * 4) = h;
    *(usx4*)(Xl + (size_t)row * CVD + t * 4) = l;
}

// ---------------- final: split-K reduce + bias -> fp32 out --------------------
__global__ __launch_bounds__(192) void reduce_out_kernel(const float* __restrict__ Cp,
                                                         const float* __restrict__ bias,
                                                         float* __restrict__ out) {
    int row = blockIdx.x, t = threadIdx.x;
    float4 y0 = ((const float4*)(Cp + (size_t)row * CTD))[t];
    float4 y1 = ((const float4*)(Cp + 786432 + (size_t)row * CTD))[t];
    float4 y2 = ((const float4*)(Cp + 1572864 + (size_t)row * CTD))[t];
    float4 y3 = ((const float4*)(Cp + 2359296 + (size_t)row * CTD))[t];
    float4 bv = ((const float4*)bias)[t];
    float4 o;
    o.x = y0.x + y1.x + y2.x + y3.x + bv.x;
    o.y = y0.y + y1.y + y2.y + y3.y + bv.y;
    o.z = y0.z + y1.z + y2.z + y3.z + bv.z;
    o.w = y0.w + y1.w + y2.w + y3.w + bv.w;
    ((float4*)(out + (size_t)row * CTD))[t] = o;
}

extern "C" void kernel_launch(void* const* d_in, const int* in_sizes, int n_in,
                              void* d_out, int out_size, void* d_ws, size_t ws_size,
                              hipStream_t stream) {
    const float* vis = (const float*)d_in[0];
    const float* inf = (const float*)d_in[1];
    const float* W0 = (const float*)d_in[3];
    const float* b0 = (const float*)d_in[4];
    const float* g0 = (const float*)d_in[5];
    const float* be0 = (const float*)d_in[6];
    const float* W1 = (const float*)d_in[7];
    const float* b1 = (const float*)d_in[8];
    const float* g1 = (const float*)d_in[9];
    const float* be1 = (const float*)d_in[10];
    const float* W2 = (const float*)d_in[11];
    const float* b2 = (const float*)d_in[12];
    const float* g2 = (const float*)d_in[13];
    const float* be2 = (const float*)d_in[14];
    const float* W3 = (const float*)d_in[15];
    const float* b3 = (const float*)d_in[16];
    float* out = (float*)d_out;

    char* ws = (char*)d_ws;
    unsigned short* x0h = (unsigned short*)(ws + 0x50000);  // 4 MB
    unsigned short* x0l = (unsigned short*)(ws + 0x450000); // 4 MB
    unsigned short* Xh = (unsigned short*)(ws + 0x850000);  // 2 MB
    unsigned short* Xl = (unsigned short*)(ws + 0xA50000);  // 2 MB
    unsigned short* W0h = (unsigned short*)(ws + 0xC50000); // 4 MB
    unsigned short* W0l = (unsigned short*)(ws + 0x1050000);
    unsigned short* W1h = (unsigned short*)(ws + 0x1450000);// 2 MB
    unsigned short* W1l = (unsigned short*)(ws + 0x1650000);
    unsigned short* W2h = (unsigned short*)(ws + 0x1850000);
    unsigned short* W2l = (unsigned short*)(ws + 0x1A50000);
    unsigned short* W3h = (unsigned short*)(ws + 0x1C50000);// 1.5 MB
    unsigned short* W3l = (unsigned short*)(ws + 0x1DD0000);
    float* Cpart = (float*)(ws + 0x1F50000);               // 16 MB

    front_kernel<<<dim3(BB), dim3(512), 0, stream>>>(vis, inf, x0h, x0l);
    wprep_all_kernel<<<dim3(1216), dim3(256), 0, stream>>>(W0, W0h, W0l, W1, W1h, W1l,
                                                           W2, W2h, W2l, W3, W3h, W3l);

    gemm_split_kernel<<<dim3(8, 8, 4), dim3(256), 0, stream>>>(x0h, x0l, W0h, W0l, Cpart, 1024, 2048, 512);
    reduce_ln_kernel<<<dim3(MROWS), dim3(256), 0, stream>>>(Cpart, b0, g0, be0, Xh, Xl);

    gemm_split_kernel<<<dim3(8, 8, 4), dim3(256), 0, stream>>>(Xh, Xl, W1h, W1l, Cpart, 1024, 1024, 256);
    reduce_ln_kernel<<<dim3(MROWS), dim3(256), 0, stream>>>(Cpart, b1, g1, be1, Xh, Xl);

    gemm_split_kernel<<<dim3(8, 8, 4), dim3(256), 0, stream>>>(Xh, Xl, W2h, W2l, Cpart, 1024, 1024, 256);
    reduce_ln_kernel<<<dim3(MROWS), dim3(256), 0, stream>>>(Cpart, b2, g2, be2, Xh, Xl);

    gemm_split_kernel<<<dim3(6, 8, 4), dim3(256), 0, stream>>>(Xh, Xl, W3h, W3l, Cpart, 768, 1024, 256);
    reduce_out_kernel<<<dim3(MROWS), dim3(192), 0, stream>>>(Cpart, b3, out);
}

// Round 9
// 650.184 us; speedup vs baseline: 1.0236x; 1.0236x over previous
//
#include <hip/hip_runtime.h>
#include <math.h>

#define BB 256
#define SS 257
#define CVD 1024
#define CTD 768
#define NTOK 256          // S-1
#define MROWS 1024        // B*4
#define EPS_LN 1e-5f
#define NEG_SLOPE 0.01f
#define LDKP 72           // LDS k-stride (64 + 8 pad) in bf16 elems -> 144B rows, 2-way banks (free)
#define NSPLIT 8          // split-K parts

typedef __bf16 bf16x8 __attribute__((ext_vector_type(8)));
typedef float f32x4 __attribute__((ext_vector_type(4)));
typedef unsigned short usx8 __attribute__((ext_vector_type(8)));
typedef unsigned short usx4 __attribute__((ext_vector_type(4)));

__device__ __forceinline__ unsigned short f2bf(float x) {
    unsigned u = __float_as_uint(x);
    unsigned r = u + 0x7FFFu + ((u >> 16) & 1u);   // round-to-nearest-even
    return (unsigned short)(r >> 16);
}
__device__ __forceinline__ float bf2f(unsigned short h) {
    return __uint_as_float(((unsigned)h) << 16);
}
__device__ __forceinline__ void cvt4(float a, float b, float c, float d, usx4& h, usx4& l) {
    h[0] = f2bf(a); l[0] = f2bf(a - bf2f(h[0]));
    h[1] = f2bf(b); l[1] = f2bf(b - bf2f(h[1]));
    h[2] = f2bf(c); l[2] = f2bf(c - bf2f(h[2]));
    h[3] = f2bf(d); l[3] = f2bf(d - bf2f(h[3]));
}

// ---------------- Phase A: cosine similarity, one wave per token-row ----------
// 16384 blocks: high TLP, BW-bound (round-2/3 proven structure).
__global__ __launch_bounds__(256) void cos_kernel(const float* __restrict__ vis,
                                                  const float* __restrict__ inf,
                                                  float* __restrict__ cosv) {
    int wave = threadIdx.x >> 6;
    int lane = threadIdx.x & 63;
    int r = blockIdx.x * 4 + wave;
    int b = r >> 8, s = r & 255;
    const float4* vrow = (const float4*)(vis + (size_t)b * SS * CVD + (size_t)(s + 1) * CVD);
    const float4* irow = (const float4*)(inf + (size_t)b * SS * CVD + (size_t)(s + 1) * CVD);
    float vv = 0.f, ii = 0.f, vi = 0.f;
#pragma unroll
    for (int j = 0; j < 4; ++j) {
        float4 v = vrow[j * 64 + lane];
        float4 w = irow[j * 64 + lane];
        vv += v.x * v.x + v.y * v.y + v.z * v.z + v.w * v.w;
        ii += w.x * w.x + w.y * w.y + w.z * w.z + w.w * w.w;
        vi += v.x * w.x + v.y * w.y + v.z * w.z + v.w * w.w;
    }
#pragma unroll
    for (int off = 32; off; off >>= 1) {
        vv += __shfl_xor(vv, off);
        ii += __shfl_xor(ii, off);
        vi += __shfl_xor(vi, off);
    }
    if (lane == 0) cosv[r] = vi / sqrtf(vv * ii);
}

// ---------------- Phase B1: top-3 per batch (ties -> lower index) -------------
__global__ __launch_bounds__(64) void topk_kernel(const float* __restrict__ cosv,
                                                  int* __restrict__ idx) {
    int b = blockIdx.x;
    int lane = threadIdx.x;
    float v[4];
    int id[4];
#pragma unroll
    for (int j = 0; j < 4; ++j) {
        id[j] = lane + j * 64;
        v[j] = cosv[b * NTOK + id[j]];
    }
    for (int round = 0; round < 3; ++round) {
        float bv = v[0];
        int bi = id[0];
#pragma unroll
        for (int j = 1; j < 4; ++j)
            if (v[j] > bv) { bv = v[j]; bi = id[j]; }
#pragma unroll
        for (int off = 32; off; off >>= 1) {
            float ov = __shfl_xor(bv, off);
            int oi = __shfl_xor(bi, off);
            if (ov > bv || (ov == bv && oi < bi)) { bv = ov; bi = oi; }
        }
        if (lane == 0) idx[b * 3 + round] = bi;
#pragma unroll
        for (int j = 0; j < 4; ++j)
            if (id[j] == bi) v[j] = -3.402823466e38f;
    }
}

// ---------------- Phase B2: gather + concat + fp32->bf16(hi,lo) ---------------
__global__ __launch_bounds__(256) void gather_conv_kernel(const float* __restrict__ vis,
                                                          const float* __restrict__ inf,
                                                          const int* __restrict__ idx,
                                                          unsigned short* __restrict__ x0h,
                                                          unsigned short* __restrict__ x0l) {
    int r = blockIdx.x, t = threadIdx.x;
    int b = r >> 2, j = r & 3;
    int tok = (j < 3) ? (idx[b * 3 + j] + 1) : 0;
    const float4* v = (const float4*)(vis + (size_t)b * SS * CVD + (size_t)tok * CVD);
    const float4* w = (const float4*)(inf + (size_t)b * SS * CVD + (size_t)tok * CVD);
    float4 a = v[t];
    float4 c = w[t];
    usx4 h, l;
    cvt4(a.x, a.y, a.z, a.w, h, l);
    *(usx4*)(x0h + (size_t)r * 2048 + t * 4) = h;
    *(usx4*)(x0l + (size_t)r * 2048 + t * 4) = l;
    cvt4(c.x, c.y, c.z, c.w, h, l);
    *(usx4*)(x0h + (size_t)r * 2048 + 1024 + t * 4) = h;
    *(usx4*)(x0l + (size_t)r * 2048 + 1024 + t * 4) = l;
}

// ============ fused weight prep: all 4 W -> bf16 hi/lo W^T ====================
__global__ __launch_bounds__(256) void wprep_all_kernel(
        const float* __restrict__ W0, unsigned short* __restrict__ W0h, unsigned short* __restrict__ W0l,
        const float* __restrict__ W1, unsigned short* __restrict__ W1h, unsigned short* __restrict__ W1l,
        const float* __restrict__ W2, unsigned short* __restrict__ W2h, unsigned short* __restrict__ W2l,
        const float* __restrict__ W3, unsigned short* __restrict__ W3h, unsigned short* __restrict__ W3l) {
    __shared__ float tile[64][69];
    int bid = blockIdx.x;
    const float* W;
    unsigned short *Th, *Tl;
    int K, N, k0, n0;
    if (bid < 512) {          // W0: 2048x1024, 32x16 tiles
        int q = bid;       W = W0; Th = W0h; Tl = W0l; K = 2048; N = 1024;
        k0 = (q & 31) * 64; n0 = (q >> 5) * 64;
    } else if (bid < 768) {   // W1: 1024x1024
        int q = bid - 512; W = W1; Th = W1h; Tl = W1l; K = 1024; N = 1024;
        k0 = (q & 15) * 64; n0 = (q >> 4) * 64;
    } else if (bid < 1024) {  // W2: 1024x1024
        int q = bid - 768; W = W2; Th = W2h; Tl = W2l; K = 1024; N = 1024;
        k0 = (q & 15) * 64; n0 = (q >> 4) * 64;
    } else {                  // W3: 1024x768, 16x12 tiles
        int q = bid - 1024; W = W3; Th = W3h; Tl = W3l; K = 1024; N = 768;
        k0 = (q & 15) * 64; n0 = (q >> 4) * 64;
    }
    int t = threadIdx.x;
    int r = t >> 4, c4 = (t & 15) * 4;
#pragma unroll
    for (int p = 0; p < 4; ++p) {
        float4 v = *(const float4*)(W + (size_t)(k0 + r + p * 16) * N + n0 + c4);
        tile[r + p * 16][c4 + 0] = v.x;
        tile[r + p * 16][c4 + 1] = v.y;
        tile[r + p * 16][c4 + 2] = v.z;
        tile[r + p * 16][c4 + 3] = v.w;
    }
    __syncthreads();
    int nn0 = t >> 4, kk = (t & 15) * 4;
#pragma unroll
    for (int p = 0; p < 4; ++p) {
        int nn = nn0 + p * 16;
        float a = tile[kk + 0][nn], b = tile[kk + 1][nn];
        float c = tile[kk + 2][nn], d = tile[kk + 3][nn];
        usx4 h, l;
        cvt4(a, b, c, d, h, l);
        *(usx4*)(Th + (size_t)(n0 + nn) * K + k0 + kk) = h;
        *(usx4*)(Tl + (size_t)(n0 + nn) * K + k0 + kk) = l;
    }
}

// ---------------- split-bf16 MFMA GEMM ----------------------------------------
// block 128x128, 4 waves of 64x64 (4x4 frags 16x16x32), BK=64, split-K NSPLIT.
// launch_bounds(256,2): 2 blocks/CU so one block's MFMA covers the other's barrier.
__global__ __launch_bounds__(256, 2) void gemm_split_kernel(
        const unsigned short* __restrict__ Ah, const unsigned short* __restrict__ Al,
        const unsigned short* __restrict__ Bh, const unsigned short* __restrict__ Bl,
        float* __restrict__ Cpart, int N, int K, int KCH) {
    __shared__ unsigned short sAh[128 * LDKP], sAl[128 * LDKP];
    __shared__ unsigned short sBh[128 * LDKP], sBl[128 * LDKP];
    int t = threadIdx.x;
    int lane = t & 63, wid = t >> 6;
    int wm = (wid >> 1) * 64, wn = (wid & 1) * 64;
    int fr = lane & 15, kg = lane >> 4;
    int m0 = blockIdx.y * 128, n0 = blockIdx.x * 128;
    int kstart = blockIdx.z * KCH;
    int sm = t >> 1, skq = (t & 1) * 32;
    const usx8* gAh = (const usx8*)(Ah + (size_t)(m0 + sm) * K + kstart + skq);
    const usx8* gAl = (const usx8*)(Al + (size_t)(m0 + sm) * K + kstart + skq);
    const usx8* gBh = (const usx8*)(Bh + (size_t)(n0 + sm) * K + kstart + skq);
    const usx8* gBl = (const usx8*)(Bl + (size_t)(n0 + sm) * K + kstart + skq);

    f32x4 acc[4][4] = {};
    usx8 rah[4], ral[4], rbh[4], rbl[4];
    int nsteps = KCH >> 6;

#pragma unroll
    for (int s = 0; s < 4; ++s) { rah[s] = gAh[s]; ral[s] = gAl[s]; rbh[s] = gBh[s]; rbl[s] = gBl[s]; }

    for (int step = 0; step < nsteps; ++step) {
        int base = sm * LDKP + skq;
#pragma unroll
        for (int s = 0; s < 4; ++s) {
            *(usx8*)&sAh[base + s * 8] = rah[s];
            *(usx8*)&sAl[base + s * 8] = ral[s];
            *(usx8*)&sBh[base + s * 8] = rbh[s];
            *(usx8*)&sBl[base + s * 8] = rbl[s];
        }
        __syncthreads();
        if (step + 1 < nsteps) {
            int adv = (step + 1) * 8;
#pragma unroll
            for (int s = 0; s < 4; ++s) {
                rah[s] = gAh[adv + s]; ral[s] = gAl[adv + s];
                rbh[s] = gBh[adv + s]; rbl[s] = gBl[adv + s];
            }
        }
#pragma unroll
        for (int kc = 0; kc < 2; ++kc) {
            int kb = kc * 32 + kg * 8;
            bf16x8 ah[4], al[4];
#pragma unroll
            for (int i = 0; i < 4; ++i) {
                int ro = (wm + i * 16 + fr) * LDKP + kb;
                ah[i] = *(const bf16x8*)&sAh[ro];
                al[i] = *(const bf16x8*)&sAl[ro];
            }
#pragma unroll
            for (int j = 0; j < 4; ++j) {
                int co = (wn + j * 16 + fr) * LDKP + kb;
                bf16x8 bh = *(const bf16x8*)&sBh[co];
                bf16x8 bl = *(const bf16x8*)&sBl[co];
#pragma unroll
                for (int i = 0; i < 4; ++i) {
                    acc[i][j] = __builtin_amdgcn_mfma_f32_16x16x32_bf16(ah[i], bh, acc[i][j], 0, 0, 0);
                    acc[i][j] = __builtin_amdgcn_mfma_f32_16x16x32_bf16(ah[i], bl, acc[i][j], 0, 0, 0);
                    acc[i][j] = __builtin_amdgcn_mfma_f32_16x16x32_bf16(al[i], bh, acc[i][j], 0, 0, 0);
                }
            }
        }
        __syncthreads();
    }
    float* Cp = Cpart + (size_t)blockIdx.z * MROWS * N;
#pragma unroll
    for (int i = 0; i < 4; ++i) {
#pragma unroll
        for (int j = 0; j < 4; ++j) {
            int row = m0 + wm + i * 16 + kg * 4;
            int col = n0 + wn + j * 16 + fr;
#pragma unroll
            for (int r = 0; r < 4; ++r)
                Cp[(size_t)(row + r) * N + col] = acc[i][j][r];
        }
    }
}

// ---------------- block reduce helper ----------------------------------------
__device__ __forceinline__ float block_sum(float x, float* red) {
#pragma unroll
    for (int off = 32; off; off >>= 1) x += __shfl_xor(x, off);
    int wave = threadIdx.x >> 6, lane = threadIdx.x & 63;
    if (lane == 0) red[wave] = x;
    __syncthreads();
    float r = red[0] + red[1] + red[2] + red[3];
    __syncthreads();
    return r;
}

// ---------------- split-K reduce (8 parts) + bias + LN + leaky + bf16(hi,lo) --
__global__ __launch_bounds__(256) void reduce_ln_kernel(const float* __restrict__ Cp,
                                                        const float* __restrict__ bias,
                                                        const float* __restrict__ g,
                                                        const float* __restrict__ be,
                                                        unsigned short* __restrict__ Xh,
                                                        unsigned short* __restrict__ Xl) {
    __shared__ float red[4];
    int row = blockIdx.x, t = threadIdx.x;
    float4 bv = ((const float4*)bias)[t];
    float vx = bv.x, vy = bv.y, vz = bv.z, vw = bv.w;
#pragma unroll
    for (int p = 0; p < NSPLIT; ++p) {
        float4 y = ((const float4*)(Cp + (size_t)p * MROWS * CVD + (size_t)row * CVD))[t];
        vx += y.x; vy += y.y; vz += y.z; vw += y.w;
    }
    float tot = block_sum(vx + vy + vz + vw, red);
    float mu = tot * (1.0f / CVD);
    float dx = vx - mu, dy = vy - mu, dz = vz - mu, dw = vw - mu;
    float tot2 = block_sum(dx * dx + dy * dy + dz * dz + dw * dw, red);
    float rstd = rsqrtf(tot2 * (1.0f / CVD) + EPS_LN);
    float4 gg = ((const float4*)g)[t];
    float4 bb = ((const float4*)be)[t];
    float ox = dx * rstd * gg.x + bb.x;
    float oy = dy * rstd * gg.y + bb.y;
    float oz = dz * rstd * gg.z + bb.z;
    float ow = dw * rstd * gg.w + bb.w;
    ox = ox >= 0.f ? ox : NEG_SLOPE * ox;
    oy = oy >= 0.f ? oy : NEG_SLOPE * oy;
    oz = oz >= 0.f ? oz : NEG_SLOPE * oz;
    ow = ow >= 0.f ? ow : NEG_SLOPE * ow;
    usx4 h, l;
    cvt4(ox, oy, oz, ow, h, l);
    *(usx4*)(Xh + (size_t)row * CVD + t * 4) = h;
    *(usx4*)(Xl + (size_t)row * CVD + t * 4) = l;
}

// ---------------- final: split-K reduce (8 parts) + bias -> fp32 out ----------
__global__ __launch_bounds__(192) void reduce_out_kernel(const float* __restrict__ Cp,
                                                         const float* __restrict__ bias,
                                                         float* __restrict__ out) {
    int row = blockIdx.x, t = threadIdx.x;
    float4 bv = ((const float4*)bias)[t];
    float4 o = bv;
#pragma unroll
    for (int p = 0; p < NSPLIT; ++p) {
        float4 y = ((const float4*)(Cp + (size_t)p * MROWS * CTD + (size_t)row * CTD))[t];
        o.x += y.x; o.y += y.y; o.z += y.z; o.w += y.w;
    }
    ((float4*)(out + (size_t)row * CTD))[t] = o;
}

extern "C" void kernel_launch(void* const* d_in, const int* in_sizes, int n_in,
                              void* d_out, int out_size, void* d_ws, size_t ws_size,
                              hipStream_t stream) {
    const float* vis = (const float*)d_in[0];
    const float* inf = (const float*)d_in[1];
    const float* W0 = (const float*)d_in[3];
    const float* b0 = (const float*)d_in[4];
    const float* g0 = (const float*)d_in[5];
    const float* be0 = (const float*)d_in[6];
    const float* W1 = (const float*)d_in[7];
    const float* b1 = (const float*)d_in[8];
    const float* g1 = (const float*)d_in[9];
    const float* be1 = (const float*)d_in[10];
    const float* W2 = (const float*)d_in[11];
    const float* b2 = (const float*)d_in[12];
    const float* g2 = (const float*)d_in[13];
    const float* be2 = (const float*)d_in[14];
    const float* W3 = (const float*)d_in[15];
    const float* b3 = (const float*)d_in[16];
    float* out = (float*)d_out;

    char* ws = (char*)d_ws;
    float* cosv = (float*)(ws + 0x0);                       // 256 KB
    int* idx = (int*)(ws + 0x40000);                        // 4 KB
    unsigned short* x0h = (unsigned short*)(ws + 0x50000);  // 4 MB
    unsigned short* x0l = (unsigned short*)(ws + 0x450000); // 4 MB
    unsigned short* Xh = (unsigned short*)(ws + 0x850000);  // 2 MB
    unsigned short* Xl = (unsigned short*)(ws + 0xA50000);  // 2 MB
    unsigned short* W0h = (unsigned short*)(ws + 0xC50000); // 4 MB
    unsigned short* W0l = (unsigned short*)(ws + 0x1050000);
    unsigned short* W1h = (unsigned short*)(ws + 0x1450000);// 2 MB
    unsigned short* W1l = (unsigned short*)(ws + 0x1650000);
    unsigned short* W2h = (unsigned short*)(ws + 0x1850000);
    unsigned short* W2l = (unsigned short*)(ws + 0x1A50000);
    unsigned short* W3h = (unsigned short*)(ws + 0x1C50000);// 1.5 MB
    unsigned short* W3l = (unsigned short*)(ws + 0x1DD0000);
    float* Cpart = (float*)(ws + 0x1F50000);                // 32 MB (8 parts)

    cos_kernel<<<dim3(16384), dim3(256), 0, stream>>>(vis, inf, cosv);
    topk_kernel<<<dim3(BB), dim3(64), 0, stream>>>(cosv, idx);
    gather_conv_kernel<<<dim3(MROWS), dim3(256), 0, stream>>>(vis, inf, idx, x0h, x0l);
    wprep_all_kernel<<<dim3(1216), dim3(256), 0, stream>>>(W0, W0h, W0l, W1, W1h, W1l,
                                                           W2, W2h, W2l, W3, W3h, W3l);

    gemm_split_kernel<<<dim3(8, 8, NSPLIT), dim3(256), 0, stream>>>(x0h, x0l, W0h, W0l, Cpart, 1024, 2048, 256);
    reduce_ln_kernel<<<dim3(MROWS), dim3(256), 0, stream>>>(Cpart, b0, g0, be0, Xh, Xl);

    gemm_split_kernel<<<dim3(8, 8, NSPLIT), dim3(256), 0, stream>>>(Xh, Xl, W1h, W1l, Cpart, 1024, 1024, 128);
    reduce_ln_kernel<<<dim3(MROWS), dim3(256), 0, stream>>>(Cpart, b1, g1, be1, Xh, Xl);

    gemm_split_kernel<<<dim3(8, 8, NSPLIT), dim3(256), 0, stream>>>(Xh, Xl, W2h, W2l, Cpart, 1024, 1024, 128);
    reduce_ln_kernel<<<dim3(MROWS), dim3(256), 0, stream>>>(Cpart, b2, g2, be2, Xh, Xl);

    gemm_split_kernel<<<dim3(6, 8, NSPLIT), dim3(256), 0, stream>>>(Xh, Xl, W3h, W3l, Cpart, 768, 1024, 128);
    reduce_out_kernel<<<dim3(MROWS), dim3(192), 0, stream>>>(Cpart, b3, out);
}